// Round 8
// baseline (5617.426 us; speedup 1.0000x reference)
//
#include <hip/hip_runtime.h>

// GC_LSTM: B=32, T=16, N=2048, HID=32. Round 3 of optimization.
//
// History:
//  R0: 1 thread/node, register arrays. 1912us, VALUBusy 23%, 1 wave/SIMD.
//  R3: 4-wave channel split + LDS exchange. 1263us, VALUBusy 81%, occ 35%.
//      BUT ~5x VALU inst overhead vs ideal + 260MB FETCH / 92MB WRITE
//      => compiler spill/shuffle of the 32-float register arrays + weight
//      restream. VGPR=64 (squeezed), scratch traffic visible.
//
// R7 fix: j-OUTER accumulation -- no large register arrays AT ALL.
//   for j in 0..31: v = LDS[j][lane] (1 ds_read, bank-conflict-free,
//   offset-immediate); 16-20 FMAs into acc[4] registers. Weight indices
//   stay wave-uniform (s_load path). KPW=4, 8 waves/block (512 thr),
//   __launch_bounds__(512,8): 64-VGPR cap, 4 blocks/CU = 32 waves/CU
//   (FULL occupancy) to hide SMEM/LDS latency.
//
// Per step: A) xn = b_out + sum8 PART  (+store out[t-1] by wave 0)
//           B) xf slice (4 ch) -> XF | bar1
//           E+F) j-outer over XF: xg[4] (ChebConv) + gates[16] accumulate
//                write relu(xg) -> XG
//           G) j-outer over HY: gates += h part
//           bar2
//           I) j-outer over XG: gates += xg part
//           J) nonlin, c update, hy -> HY, fc_out partial -> PART | bar3

#define B_ 32
#define T_ 16
#define N_ 2048
#define H_ 32
#define NPB 64   // nodes per block (= lanes)
#define WPB 8    // waves per block
#define KPW 4    // channels per wave

__device__ __forceinline__ float fast_rcp(float x) { return __builtin_amdgcn_rcpf(x); }
__device__ __forceinline__ float sigmoid_f(float x) { return fast_rcp(1.0f + __expf(-x)); }
__device__ __forceinline__ float tanh_f(float x) {
    return fmaf(-2.0f, fast_rcp(1.0f + __expf(2.0f * x)), 1.0f);
}

__global__ __launch_bounds__(512, 8) void gclstm_kernel(
    const float* __restrict__ x,      // [B,T,N]
    const float* __restrict__ W_in,   // [32,1]
    const float* __restrict__ b_in,   // [32]
    const float* __restrict__ W_gc,   // [32,32]
    const float* __restrict__ b_gc,   // [32]
    const float* __restrict__ W_x2h,  // [128,64]
    const float* __restrict__ b_x2h,  // [128]
    const float* __restrict__ W_h2h,  // [128,32]
    const float* __restrict__ b_h2h,  // [128]
    const float* __restrict__ W_out,  // [1,32]
    const float* __restrict__ b_out,  // [1]
    float* __restrict__ out)          // [B,T,N]
{
    __shared__ float XF[H_][NPB];     // 8KB
    __shared__ float XG[H_][NPB];     // 8KB
    __shared__ float HY[H_][NPB];     // 8KB
    __shared__ float PART[WPB][NPB];  // 2KB

    const int lane = threadIdx.x & 63;
    // wid is wave-uniform; readfirstlane pins it to an SGPR so every weight
    // index below is provably uniform -> s_load (SMEM pipe), not VMEM.
    const int wid = __builtin_amdgcn_readfirstlane((int)(threadIdx.x >> 6));
    const int ch0 = wid * KPW;        // this wave's first channel
    const int node = blockIdx.x * NPB + lane;
    const int b = node >> 11;         // / N_
    const int n = node & (N_ - 1);

#pragma unroll
    for (int k = 0; k < KPW; ++k) HY[ch0 + k][lane] = 0.0f;
    PART[wid][lane] = 0.0f;

    float c[KPW];
#pragma unroll
    for (int k = 0; k < KPW; ++k) c[k] = 0.0f;

    const float x0 = x[b * (T_ * N_) + n];   // only element of x ever used
    float* outp = out + b * (T_ * N_) + n;
    const float bo = b_out[0];

    __syncthreads();

#pragma unroll 1
    for (int t = 0; t < T_; ++t) {
        // ---- A: xn = fc_out(h(t)); also IS out[t-1] ----
        float xn = bo;
#pragma unroll
        for (int w = 0; w < WPB; ++w) xn += PART[w][lane];
        if (t == 0) {
            xn = x0;
        } else if (wid == 0) {
            outp[(t - 1) * N_] = xn;    // coalesced across lanes
        }

        // ---- B: fc_in + relu, this wave's 4 channels ----
#pragma unroll
        for (int k = 0; k < KPW; ++k) {
            XF[ch0 + k][lane] = fmaxf(fmaf(xn, W_in[ch0 + k], b_in[ch0 + k]), 0.0f);
        }
        __syncthreads();   // bar1: XF complete

        // ---- E+F fused, j-outer over XF: ChebConv acc + gate acc(xf) ----
        float xg[KPW], gi[KPW], gf[KPW], gg[KPW], go[KPW];
#pragma unroll
        for (int k = 0; k < KPW; ++k) {
            const int ch = ch0 + k;
            xg[k] = b_gc[ch];
            gi[k] = b_x2h[ch]      + b_h2h[ch];
            gf[k] = b_x2h[32 + ch] + b_h2h[32 + ch];
            gg[k] = b_x2h[64 + ch] + b_h2h[64 + ch];
            go[k] = b_x2h[96 + ch] + b_h2h[96 + ch];
        }
#pragma unroll
        for (int j = 0; j < H_; ++j) {
            const float v = XF[j][lane];   // 1 ds_read feeds 20 FMAs
#pragma unroll
            for (int k = 0; k < KPW; ++k) {
                const int ch = ch0 + k;
                xg[k] = fmaf(v, W_gc[ch * H_ + j], xg[k]);
                gi[k] = fmaf(v, W_x2h[(ch     ) * 64 + j], gi[k]);
                gf[k] = fmaf(v, W_x2h[(ch + 32) * 64 + j], gf[k]);
                gg[k] = fmaf(v, W_x2h[(ch + 64) * 64 + j], gg[k]);
                go[k] = fmaf(v, W_x2h[(ch + 96) * 64 + j], go[k]);
            }
        }
#pragma unroll
        for (int k = 0; k < KPW; ++k) {
            XG[ch0 + k][lane] = fmaxf(xg[k], 0.0f);   // xg regs die here
        }

        // ---- G: j-outer over HY (h(t), written last step; safe: pre-bar2) ----
#pragma unroll
        for (int j = 0; j < H_; ++j) {
            const float v = HY[j][lane];
#pragma unroll
            for (int k = 0; k < KPW; ++k) {
                const int ch = ch0 + k;
                gi[k] = fmaf(v, W_h2h[(ch     ) * H_ + j], gi[k]);
                gf[k] = fmaf(v, W_h2h[(ch + 32) * H_ + j], gf[k]);
                gg[k] = fmaf(v, W_h2h[(ch + 64) * H_ + j], gg[k]);
                go[k] = fmaf(v, W_h2h[(ch + 96) * H_ + j], go[k]);
            }
        }
        __syncthreads();   // bar2: XG complete; all HY reads done

        // ---- I: j-outer over XG: gate acc(xg) ----
#pragma unroll
        for (int j = 0; j < H_; ++j) {
            const float v = XG[j][lane];
#pragma unroll
            for (int k = 0; k < KPW; ++k) {
                const int ch = ch0 + k;
                gi[k] = fmaf(v, W_x2h[(ch     ) * 64 + 32 + j], gi[k]);
                gf[k] = fmaf(v, W_x2h[(ch + 32) * 64 + 32 + j], gf[k]);
                gg[k] = fmaf(v, W_x2h[(ch + 64) * 64 + 32 + j], gg[k]);
                go[k] = fmaf(v, W_x2h[(ch + 96) * 64 + 32 + j], go[k]);
            }
        }

        // ---- J: nonlinearity, cell update, hy -> HY, fc_out partial ----
        float part = 0.0f;
#pragma unroll
        for (int k = 0; k < KPW; ++k) {
            const float cy = fmaf(c[k], sigmoid_f(gf[k]), sigmoid_f(gi[k]) * tanh_f(gg[k]));
            c[k] = cy;
            const float hyv = sigmoid_f(go[k]) * tanh_f(cy);
            HY[ch0 + k][lane] = hyv;     // safe: HY reads ended at bar2
            part = fmaf(hyv, W_out[ch0 + k], part);
        }
        PART[wid][lane] = part;
        __syncthreads();   // bar3: HY/PART complete -> next step
    }

    // ---- epilogue: out[T-1] ----
    if (wid == 0) {
        float xn = bo;
#pragma unroll
        for (int w = 0; w < WPB; ++w) xn += PART[w][lane];
        outp[(T_ - 1) * N_] = xn;
    }
}

extern "C" void kernel_launch(void* const* d_in, const int* in_sizes, int n_in,
                              void* d_out, int out_size, void* d_ws, size_t ws_size,
                              hipStream_t stream) {
    // setup_inputs() order:
    // 0:x 1:A_q 2:A_h 3:A 4:W_in 5:b_in 6:W_gc 7:b_gc
    // 8:W_x2h 9:b_x2h 10:W_h2h 11:b_h2h 12:W_out 13:b_out
    const float* x     = (const float*)d_in[0];
    const float* W_in  = (const float*)d_in[4];
    const float* b_in  = (const float*)d_in[5];
    const float* W_gc  = (const float*)d_in[6];
    const float* b_gc  = (const float*)d_in[7];
    const float* W_x2h = (const float*)d_in[8];
    const float* b_x2h = (const float*)d_in[9];
    const float* W_h2h = (const float*)d_in[10];
    const float* b_h2h = (const float*)d_in[11];
    const float* W_out = (const float*)d_in[12];
    const float* b_out = (const float*)d_in[13];
    float* out = (float*)d_out;

    dim3 block(512);                       // 8 waves
    dim3 grid((B_ * N_) / NPB);            // 1024 blocks = 4 per CU (exactly resident)

    gclstm_kernel<<<grid, block, 0, stream>>>(
        x, W_in, b_in, W_gc, b_gc, W_x2h, b_x2h, W_h2h, b_h2h,
        W_out, b_out, out);
}

// Round 10
// 5330.555 us; speedup vs baseline: 1.0538x; 1.0538x over previous
//
#include <hip/hip_runtime.h>

// GC_LSTM: B=32, T=16, N=2048, HID=32. Round 4 of optimization.
//
// History:
//  R0: 1 thread/node, reg arrays.          1912us, VALU 23%, latency-bound.
//  R3: 4-wave chan-split, reg arrays.      1263us, VALU 81%, but 260MB FETCH
//      + 92MB WRITE => spill traffic.
//  R7: j-outer, launch_bounds(512,8).      5617us REGRESSION. VGPR capped at
//      32 => all accumulators spilled (113MB WRITE, 123MB FETCH = scratch
//      round-trips, 26ms cold dispatch). Lesson: don't buy occupancy with
//      registers the inner loop needs (Guideline 6).
//
// R8 fix: SAME j-outer structure, launch_bounds(512,4) => 128-VGPR cap.
//   ~24 live accumulators fit comfortably; no spill. 2 blocks/CU x 8 waves
//   = 16 waves/CU. Weights stay on the wave-uniform s_load path; XF/XG/HY
//   exchanged via LDS, 3 barriers/step; 1 ds_read feeds 20 FMAs.
//
// Diagnostic for success: WRITE_SIZE collapses 113MB -> ~4-6MB.

#define B_ 32
#define T_ 16
#define N_ 2048
#define H_ 32
#define NPB 64   // nodes per block (= lanes)
#define WPB 8    // waves per block
#define KPW 4    // channels per wave

__device__ __forceinline__ float fast_rcp(float x) { return __builtin_amdgcn_rcpf(x); }
__device__ __forceinline__ float sigmoid_f(float x) { return fast_rcp(1.0f + __expf(-x)); }
__device__ __forceinline__ float tanh_f(float x) {
    return fmaf(-2.0f, fast_rcp(1.0f + __expf(2.0f * x)), 1.0f);
}

__global__ __launch_bounds__(512, 4) void gclstm_kernel(
    const float* __restrict__ x,      // [B,T,N]
    const float* __restrict__ W_in,   // [32,1]
    const float* __restrict__ b_in,   // [32]
    const float* __restrict__ W_gc,   // [32,32]
    const float* __restrict__ b_gc,   // [32]
    const float* __restrict__ W_x2h,  // [128,64]
    const float* __restrict__ b_x2h,  // [128]
    const float* __restrict__ W_h2h,  // [128,32]
    const float* __restrict__ b_h2h,  // [128]
    const float* __restrict__ W_out,  // [1,32]
    const float* __restrict__ b_out,  // [1]
    float* __restrict__ out)          // [B,T,N]
{
    __shared__ float XF[H_][NPB];     // 8KB
    __shared__ float XG[H_][NPB];     // 8KB
    __shared__ float HY[H_][NPB];     // 8KB
    __shared__ float PART[WPB][NPB];  // 2KB

    const int lane = threadIdx.x & 63;
    // wid is wave-uniform; readfirstlane pins it to an SGPR so every weight
    // index below is provably uniform -> s_load (SMEM pipe), not VMEM.
    const int wid = __builtin_amdgcn_readfirstlane((int)(threadIdx.x >> 6));
    const int ch0 = wid * KPW;        // this wave's first channel
    const int node = blockIdx.x * NPB + lane;
    const int b = node >> 11;         // / N_
    const int n = node & (N_ - 1);

#pragma unroll
    for (int k = 0; k < KPW; ++k) HY[ch0 + k][lane] = 0.0f;
    PART[wid][lane] = 0.0f;

    float c[KPW];
#pragma unroll
    for (int k = 0; k < KPW; ++k) c[k] = 0.0f;

    const float x0 = x[b * (T_ * N_) + n];   // only element of x ever used
    float* outp = out + b * (T_ * N_) + n;
    const float bo = b_out[0];

    __syncthreads();

#pragma unroll 1
    for (int t = 0; t < T_; ++t) {
        // ---- A: xn = fc_out(h(t)); also IS out[t-1] ----
        float xn = bo;
#pragma unroll
        for (int w = 0; w < WPB; ++w) xn += PART[w][lane];
        if (t == 0) {
            xn = x0;
        } else if (wid == 0) {
            outp[(t - 1) * N_] = xn;    // coalesced across lanes
        }

        // ---- B: fc_in + relu, this wave's 4 channels ----
#pragma unroll
        for (int k = 0; k < KPW; ++k) {
            XF[ch0 + k][lane] = fmaxf(fmaf(xn, W_in[ch0 + k], b_in[ch0 + k]), 0.0f);
        }
        __syncthreads();   // bar1: XF complete

        // ---- E+F fused, j-outer over XF: ChebConv acc + gate acc(xf) ----
        float xg[KPW], gi[KPW], gf[KPW], gg[KPW], go[KPW];
#pragma unroll
        for (int k = 0; k < KPW; ++k) {
            const int ch = ch0 + k;
            xg[k] = b_gc[ch];
            gi[k] = b_x2h[ch]      + b_h2h[ch];
            gf[k] = b_x2h[32 + ch] + b_h2h[32 + ch];
            gg[k] = b_x2h[64 + ch] + b_h2h[64 + ch];
            go[k] = b_x2h[96 + ch] + b_h2h[96 + ch];
        }
#pragma unroll
        for (int j = 0; j < H_; ++j) {
            const float v = XF[j][lane];   // 1 ds_read feeds 20 FMAs
#pragma unroll
            for (int k = 0; k < KPW; ++k) {
                const int ch = ch0 + k;
                xg[k] = fmaf(v, W_gc[ch * H_ + j], xg[k]);
                gi[k] = fmaf(v, W_x2h[(ch     ) * 64 + j], gi[k]);
                gf[k] = fmaf(v, W_x2h[(ch + 32) * 64 + j], gf[k]);
                gg[k] = fmaf(v, W_x2h[(ch + 64) * 64 + j], gg[k]);
                go[k] = fmaf(v, W_x2h[(ch + 96) * 64 + j], go[k]);
            }
        }
#pragma unroll
        for (int k = 0; k < KPW; ++k) {
            XG[ch0 + k][lane] = fmaxf(xg[k], 0.0f);   // xg regs die here
        }

        // ---- G: j-outer over HY (h(t), written last step; safe: pre-bar2) ----
#pragma unroll
        for (int j = 0; j < H_; ++j) {
            const float v = HY[j][lane];
#pragma unroll
            for (int k = 0; k < KPW; ++k) {
                const int ch = ch0 + k;
                gi[k] = fmaf(v, W_h2h[(ch     ) * H_ + j], gi[k]);
                gf[k] = fmaf(v, W_h2h[(ch + 32) * H_ + j], gf[k]);
                gg[k] = fmaf(v, W_h2h[(ch + 64) * H_ + j], gg[k]);
                go[k] = fmaf(v, W_h2h[(ch + 96) * H_ + j], go[k]);
            }
        }
        __syncthreads();   // bar2: XG complete; all HY reads done

        // ---- I: j-outer over XG: gate acc(xg) ----
#pragma unroll
        for (int j = 0; j < H_; ++j) {
            const float v = XG[j][lane];
#pragma unroll
            for (int k = 0; k < KPW; ++k) {
                const int ch = ch0 + k;
                gi[k] = fmaf(v, W_x2h[(ch     ) * 64 + 32 + j], gi[k]);
                gf[k] = fmaf(v, W_x2h[(ch + 32) * 64 + 32 + j], gf[k]);
                gg[k] = fmaf(v, W_x2h[(ch + 64) * 64 + 32 + j], gg[k]);
                go[k] = fmaf(v, W_x2h[(ch + 96) * 64 + 32 + j], go[k]);
            }
        }

        // ---- J: nonlinearity, cell update, hy -> HY, fc_out partial ----
        float part = 0.0f;
#pragma unroll
        for (int k = 0; k < KPW; ++k) {
            const float cy = fmaf(c[k], sigmoid_f(gf[k]), sigmoid_f(gi[k]) * tanh_f(gg[k]));
            c[k] = cy;
            const float hyv = sigmoid_f(go[k]) * tanh_f(cy);
            HY[ch0 + k][lane] = hyv;     // safe: HY reads ended at bar2
            part = fmaf(hyv, W_out[ch0 + k], part);
        }
        PART[wid][lane] = part;
        __syncthreads();   // bar3: HY/PART complete -> next step
    }

    // ---- epilogue: out[T-1] ----
    if (wid == 0) {
        float xn = bo;
#pragma unroll
        for (int w = 0; w < WPB; ++w) xn += PART[w][lane];
        outp[(T_ - 1) * N_] = xn;
    }
}

extern "C" void kernel_launch(void* const* d_in, const int* in_sizes, int n_in,
                              void* d_out, int out_size, void* d_ws, size_t ws_size,
                              hipStream_t stream) {
    // setup_inputs() order:
    // 0:x 1:A_q 2:A_h 3:A 4:W_in 5:b_in 6:W_gc 7:b_gc
    // 8:W_x2h 9:b_x2h 10:W_h2h 11:b_h2h 12:W_out 13:b_out
    const float* x     = (const float*)d_in[0];
    const float* W_in  = (const float*)d_in[4];
    const float* b_in  = (const float*)d_in[5];
    const float* W_gc  = (const float*)d_in[6];
    const float* b_gc  = (const float*)d_in[7];
    const float* W_x2h = (const float*)d_in[8];
    const float* b_x2h = (const float*)d_in[9];
    const float* W_h2h = (const float*)d_in[10];
    const float* b_h2h = (const float*)d_in[11];
    const float* W_out = (const float*)d_in[12];
    const float* b_out = (const float*)d_in[13];
    float* out = (float*)d_out;

    dim3 block(512);                       // 8 waves
    dim3 grid((B_ * N_) / NPB);            // 1024 blocks

    gclstm_kernel<<<grid, block, 0, stream>>>(
        x, W_in, b_in, W_gc, b_gc, W_x2h, b_x2h, W_h2h, b_h2h,
        W_out, b_out, out);
}